// Round 16
// baseline (28.949 us; speedup 1.0000x reference)
//
#include <hip/hip_runtime.h>
#include <math.h>

// Problem constants (from setup_inputs)
#define NG    1000   // num_graphs
#define NPG   128    // nodes_per_graph
#define FF    59     // features
#define D1    128    // hidden 1
#define D2    256    // hidden 2
#define EPSV  1e-5f

// NOTE on the neighbor graph: the reference's  d2 + eye(n)*inf  makes every
// OFF-diagonal entry 0*inf = NaN (diag = +inf); top_k(-d2) then selects,
// stably, the 3 lowest indices != i:
//   idx[i] = {0,1,2} for i>=3;  {1,2,3}, {0,2,3}, {0,1,3} for i=0,1,2.
// So v_j = x_j @ w1b is only needed for j in {0,1,2,3}, and
//   sum_edges relu(u_i + v_j) = sum_i S3(i) + sum_{i<3} [relu(u_i+v3) - relu(u_i+v_i)]
// where S3(i) = relu(u_i+v0)+relu(u_i+v1)+relu(u_i+v2),
//       u_i = x_i @ (w1a - w1b) + b1   (b1 folded into wu's k=59 row, x pad=1.0)
//
// Round-16: R15 (best, 24.96) + head-MLP diet: blob kernel additionally emits
// w2 TRANSPOSED in bf16 (w2t[256][128], 65 KB). Head reads its output-dim row
// contiguously: 16 dwordx4/thread instead of 128 scalar dwords, and w2 L2
// bytes halve (the head's 131 KB/block fp32 column-read was the largest
// per-CU bandwidth term: ~4 us/CU at 4 blocks/CU).

typedef short  short8  __attribute__((ext_vector_type(8)));
typedef float  f32x4   __attribute__((ext_vector_type(4)));

#define WS_WB_SHORTS  8192    // wb blob at short offset 8192  (byte 16384)
#define WS_W2T_SHORTS 16384   // w2t blob at short offset 16384 (byte 32768), 65536 B

static __device__ __forceinline__ unsigned short f2bf(float f) {
    union { float f; unsigned u; } v; v.f = f;
    unsigned r = v.u + 0x7FFFu + ((v.u >> 16) & 1u);   // RNE
    return (unsigned short)(r >> 16);
}
static __device__ __forceinline__ float bf2f(unsigned short h) {
    union { unsigned u; float f; } v; v.u = ((unsigned)h) << 16; return v.f;
}

// Build one row's two k-step A-fragments from the LDS x-image.
// k=59 -> 1.0 (bias row; wb blob has 0 there so vv is unaffected), k>59 -> 0.
static __device__ __forceinline__ void frags_from_lds(
    const float* __restrict__ xs, int row, int lg, short8* a)
{
    const float* r = xs + row * FF;
    float xv[8];
    #pragma unroll
    for (int j = 0; j < 8; ++j) xv[j] = r[lg * 8 + j];
    #pragma unroll
    for (int j = 0; j < 8; ++j) a[0][j] = (short)f2bf(xv[j]);
    if (lg < 3) {
        #pragma unroll
        for (int j = 0; j < 8; ++j) xv[j] = r[32 + lg * 8 + j];
    } else {
        xv[0] = r[56]; xv[1] = r[57]; xv[2] = r[58]; xv[3] = 1.0f;
        #pragma unroll
        for (int j = 4; j < 8; ++j) xv[j] = 0.0f;
    }
    #pragma unroll
    for (int j = 0; j < 8; ++j) a[1][j] = (short)f2bf(xv[j]);
}

// ---------------------------------------------------------------------------
// Kernel B (48 wgs x 64 thr):
//  wgs 0..15  : wu fragments (w1a-w1b, bias row k=59)
//  wgs 16..31 : wb fragments (w1b, zero at k=59)
//  wgs 32..47 : w2t rows — w2t[d][f] = bf16(w2[f][d]), 16 rows per wg
// ---------------------------------------------------------------------------
__global__ __launch_bounds__(64) void ecn_blob(
    const float* __restrict__ w1, const float* __restrict__ b1,
    const float* __restrict__ w2, short* __restrict__ blob)
{
    const int bid = blockIdx.x;
    const int l = threadIdx.x;
    if (bid < 32) {
        const bool isB = (bid >= 16);
        const int fid = isB ? (bid - 16) : bid;
        const int s = fid >> 3, nt = fid & 7;
        const int lr = l & 15, lg = l >> 4;
        const int d = nt * 16 + lr, k0 = s * 32 + lg * 8;
        short8 pk;
        #pragma unroll
        for (int j = 0; j < 8; ++j) {
            int k = k0 + j;
            float v = 0.0f;
            if (k < FF) {
                float wb_ = w1[(size_t)(FF + k) * D1 + d];
                v = isB ? wb_ : (w1[(size_t)k * D1 + d] - wb_);
            } else if (k == FF && !isB) {
                v = b1[d];                   // bias row only in wu
            }
            pk[j] = (short)f2bf(v);
        }
        *(short8*)&blob[(size_t)(isB ? WS_WB_SHORTS : 0) + ((s * 8 + nt) * 64 + l) * 8] = pk;
    } else {
        // w2t: wg handles 16 output dims; thread: dim r = base+(l&15), k-chunk c = l>>4
        const int r = (bid - 32) * 16 + (l & 15);
        const int c = l >> 4;                // 4 chunks of 32 k
        short* dst = blob + WS_W2T_SHORTS + (size_t)r * D1 + c * 32;
        #pragma unroll
        for (int q = 0; q < 4; ++q) {        // 4 x short8 = 32 k
            short8 pk;
            #pragma unroll
            for (int j = 0; j < 8; ++j) {
                int f = c * 32 + q * 8 + j;
                pk[j] = (short)f2bf(w2[(size_t)f * D2 + r]);
            }
            *(short8*)&dst[q * 8] = pk;
        }
    }
}

// ---------------------------------------------------------------------------
// Kernel F: per-graph fused. Coalesced LDS x-staging + distributed vv +
// per-nt streaming u-GEMM + epilogue + BN1 + bf16 head MLP + sigmoid.
// ---------------------------------------------------------------------------
__global__ __launch_bounds__(256, 4) void ecn_fused(
    const float* __restrict__ x, const short* __restrict__ blob,
    const float* __restrict__ g1, const float* __restrict__ be1,
    const float* __restrict__ m1, const float* __restrict__ v1,
    const float* __restrict__ b2,
    const float* __restrict__ g2, const float* __restrict__ be2,
    const float* __restrict__ m2, const float* __restrict__ v2,
    const float* __restrict__ w3, const float* __restrict__ b3,
    const float* __restrict__ g3, const float* __restrict__ be3,
    const float* __restrict__ m3, const float* __restrict__ v3,
    float* __restrict__ out)
{
    const int g = blockIdx.x;
    const int t = threadIdx.x;

    __shared__ __align__(16) float xs[NPG * FF];   // 30208 B, linear f32 image
    __shared__ float vvsh[4 * D1];   // 2 KB
    __shared__ float Sp[4][D1];      // 2 KB
    __shared__ float x2s[D1];        // 512 B
    __shared__ float rpart[4];
    // total ~35 KB -> 4 blocks/CU

    // ---- stage x: 1888 float4 chunks, coalesced dwordx4, linear b128 writes ----
    {
        const float4* xg4 = (const float4*)(x + (size_t)g * NPG * FF);
        float4* xs4 = (float4*)xs;
        #pragma unroll
        for (int k = 0; k < 8; ++k) {
            int e = t + k * 256;
            if (k < 7 || e < 1888) xs4[e] = xg4[e];
        }
    }
    __syncthreads();

    const int wave = t >> 6, l = t & 63;
    const int lr = l & 15, lg = l >> 4;
    const int i0 = wave * 32 + lr;        // mt=0 row
    const int i1 = i0 + 16;               // mt=1 row

    const short8* wu8 = (const short8*)blob;
    const short8* wb8 = (const short8*)(blob + WS_WB_SHORTS);

    // ---- A fragments from LDS: rows i0, i1 (u-GEMM) and row lr (vv tile) ----
    short8 a0[2], a1[2], av[2];
    frags_from_lds(xs, i0, lg, a0);
    frags_from_lds(xs, i1, lg, a1);
    if (wave == 0) { av[0] = a0[0]; av[1] = a0[1]; }   // wave 0: lr == i0
    else           frags_from_lds(xs, lr, lg, av);

    // ---- vv: this wave computes nt-tiles {2*wave, 2*wave+1} of x_{0..15}@w1b ----
    #pragma unroll
    for (int p = 0; p < 2; ++p) {
        const int nt = wave * 2 + p;
        f32x4 cv = (f32x4)0.0f;
        cv = __builtin_amdgcn_mfma_f32_16x16x32_bf16(av[0], wb8[nt * 64 + l],       cv, 0, 0, 0);
        cv = __builtin_amdgcn_mfma_f32_16x16x32_bf16(av[1], wb8[(8 + nt) * 64 + l], cv, 0, 0, 0);
        if (lg == 0) {                    // rows 0..3 = lanes 0..15, q=0..3
            #pragma unroll
            for (int q = 0; q < 4; ++q) vvsh[q * D1 + nt * 16 + lr] = cv[q];
        }
    }
    __syncthreads();                      // vvsh complete

    // ---- per-nt streaming u-GEMM + fused relu-edge aggregation ----
    #pragma unroll
    for (int nt = 0; nt < 8; ++nt) {
        short8 b0 = wu8[nt * 64 + l];
        short8 b1f = wu8[(8 + nt) * 64 + l];
        f32x4 c0 = (f32x4)0.0f, c1 = (f32x4)0.0f;
        c0 = __builtin_amdgcn_mfma_f32_16x16x32_bf16(a0[0], b0,  c0, 0, 0, 0);
        c0 = __builtin_amdgcn_mfma_f32_16x16x32_bf16(a0[1], b1f, c0, 0, 0, 0);
        c1 = __builtin_amdgcn_mfma_f32_16x16x32_bf16(a1[0], b0,  c1, 0, 0, 0);
        c1 = __builtin_amdgcn_mfma_f32_16x16x32_bf16(a1[1], b1f, c1, 0, 0, 0);

        const int d = nt * 16 + lr;
        const float v0 = vvsh[d], v1_ = vvsh[128 + d], v2_ = vvsh[256 + d], v3_ = vvsh[384 + d];
        float s = 0.0f;
        #pragma unroll
        for (int q = 0; q < 4; ++q) {
            float u = c0[q];              // b1 already inside via k=59 row
            s += fmaxf(u + v0, 0.0f) + fmaxf(u + v1_, 0.0f) + fmaxf(u + v2_, 0.0f);
            u = c1[q];
            s += fmaxf(u + v0, 0.0f) + fmaxf(u + v1_, 0.0f) + fmaxf(u + v2_, 0.0f);
        }
        if (wave == 0 && lg == 0) {       // global rows 0,1,2 = c0 q=0..2
            float u0 = c0[0], u1 = c0[1], u2 = c0[2];
            s += fmaxf(u0 + v3_, 0.0f) - fmaxf(u0 + v0,  0.0f);
            s += fmaxf(u1 + v3_, 0.0f) - fmaxf(u1 + v1_, 0.0f);
            s += fmaxf(u2 + v3_, 0.0f) - fmaxf(u2 + v2_, 0.0f);
        }
        s += __shfl_xor(s, 16);
        s += __shfl_xor(s, 32);
        if (lg == 0) Sp[wave][d] = s;
    }
    __syncthreads();

    // ---- BN1 (affine commutes with the means) -> x2 in LDS ----
    if (t < D1) {
        float tot = Sp[0][t] + Sp[1][t] + Sp[2][t] + Sp[3][t];
        float sc = g1[t] * rsqrtf(v1[t] + EPSV);
        x2s[t] = sc * (tot * (1.0f / (3 * NPG))) + (be1[t] - m1[t] * sc);
    }
    __syncthreads();

    // ---- head MLP + sigmoid: bf16 w2t rows, 16 dwordx4/thread ----
    {
        const short* w2row = blob + WS_W2T_SHORTS + (size_t)t * D1;
        float h0 = b2[t], h1 = 0.0f, h2 = 0.0f, h3 = 0.0f;
        #pragma unroll
        for (int c = 0; c < 16; ++c) {
            short8 wv = *(const short8*)&w2row[c * 8];
            const int f = c * 8;
            h0 = fmaf(x2s[f + 0], bf2f((unsigned short)wv[0]), h0);
            h1 = fmaf(x2s[f + 1], bf2f((unsigned short)wv[1]), h1);
            h2 = fmaf(x2s[f + 2], bf2f((unsigned short)wv[2]), h2);
            h3 = fmaf(x2s[f + 3], bf2f((unsigned short)wv[3]), h3);
            h0 = fmaf(x2s[f + 4], bf2f((unsigned short)wv[4]), h0);
            h1 = fmaf(x2s[f + 5], bf2f((unsigned short)wv[5]), h1);
            h2 = fmaf(x2s[f + 6], bf2f((unsigned short)wv[6]), h2);
            h3 = fmaf(x2s[f + 7], bf2f((unsigned short)wv[7]), h3);
        }
        float h = (h0 + h1) + (h2 + h3);
        h = fmaxf(h, 0.0f);
        float sc2 = g2[t] * rsqrtf(v2[t] + EPSV);
        h = sc2 * h + (be2[t] - m2[t] * sc2);
        float r = h * w3[t];
        #pragma unroll
        for (int off = 32; off > 0; off >>= 1) r += __shfl_down(r, off);
        if ((t & 63) == 0) rpart[t >> 6] = r;
    }
    __syncthreads();
    if (t == 0) {
        float s = rpart[0] + rpart[1] + rpart[2] + rpart[3] + b3[0];
        s = fmaxf(s, 0.0f);
        float sc3 = g3[0] * rsqrtf(v3[0] + EPSV);
        s = sc3 * s + (be3[0] - m3[0] * sc3);
        out[g] = 1.0f / (1.0f + expf(-s));
    }
}

extern "C" void kernel_launch(void* const* d_in, const int* in_sizes, int n_in,
                              void* d_out, int out_size, void* d_ws, size_t ws_size,
                              hipStream_t stream) {
    const float* x   = (const float*)d_in[0];
    // d_in[1] = pos — unused: the reference's knn degenerates (see NOTE)
    const float* w1  = (const float*)d_in[2];
    const float* b1  = (const float*)d_in[3];
    const float* g1  = (const float*)d_in[4];
    const float* be1 = (const float*)d_in[5];
    const float* m1  = (const float*)d_in[6];
    const float* v1  = (const float*)d_in[7];
    const float* w2  = (const float*)d_in[8];
    const float* b2  = (const float*)d_in[9];
    const float* g2  = (const float*)d_in[10];
    const float* be2 = (const float*)d_in[11];
    const float* m2  = (const float*)d_in[12];
    const float* v2  = (const float*)d_in[13];
    const float* w3  = (const float*)d_in[14];
    const float* b3  = (const float*)d_in[15];
    const float* g3  = (const float*)d_in[16];
    const float* be3 = (const float*)d_in[17];
    const float* m3  = (const float*)d_in[18];
    const float* v3  = (const float*)d_in[19];
    float* outp = (float*)d_out;

    short* blob = (short*)d_ws;

    ecn_blob<<<48, 64, 0, stream>>>(w1, b1, w2, blob);
    ecn_fused<<<NG, 256, 0, stream>>>(x, blob, g1, be1, m1, v1,
                                      b2, g2, be2, m2, v2,
                                      w3, b3, g3, be3, m3, v3, outp);
}

// Round 17
// 23.432 us; speedup vs baseline: 1.2354x; 1.2354x over previous
//
#include <hip/hip_runtime.h>
#include <math.h>

// Problem constants (from setup_inputs)
#define NG    1000   // num_graphs
#define NPG   128    // nodes_per_graph
#define FF    59     // features
#define D1    128    // hidden 1
#define D2    256    // hidden 2
#define EPSV  1e-5f

// NOTE on the neighbor graph: the reference's  d2 + eye(n)*inf  makes every
// OFF-diagonal entry 0*inf = NaN (diag = +inf); top_k(-d2) then selects,
// stably, the 3 lowest indices != i:
//   idx[i] = {0,1,2} for i>=3;  {1,2,3}, {0,2,3}, {0,1,3} for i=0,1,2.
// So v_j = x_j @ w1b is only needed for j in {0,1,2,3}, and
//   sum_edges relu(u_i + v_j) = sum_i S3(i) + sum_{i<3} [relu(u_i+v3) - relu(u_i+v_i)]
// where S3(i) = relu(u_i+v0)+relu(u_i+v1)+relu(u_i+v2),
//       u_i = x_i @ (w1a - w1b) + b1   (b1 folded into wu's k=59 row, x pad=1.0)
//
// Round-17: R15 body (best, 24.96) + two locality/issue fixes:
//  (1) XCD-aware bijective blockIdx swizzle g=(bid&7)*125+(bid>>3): each XCD's
//      4MB L2 then serves a contiguous ~3.7MB x-chunk (fits!) instead of a
//      sparse sample of all 30MB -> steady-state replays hit L2 not HBM.
//  (2) x staging via global_load_lds (wave-uniform base + lane*16 linear
//      layout matches the HW pattern exactly) -> direct-to-LDS DMA, no VGPR
//      round-trip.
// R16's w2t head reverted (blob-side strided gather + head unpack VALU lost).

typedef short  short8  __attribute__((ext_vector_type(8)));
typedef float  f32x4   __attribute__((ext_vector_type(4)));

#define WS_WB_SHORTS 8192   // wb blob starts at short offset 8192 (16 KB)

static __device__ __forceinline__ unsigned short f2bf(float f) {
    union { float f; unsigned u; } v; v.f = f;
    unsigned r = v.u + 0x7FFFu + ((v.u >> 16) & 1u);   // RNE
    return (unsigned short)(r >> 16);
}

// Build one row's two k-step A-fragments from the LDS x-image.
// k=59 -> 1.0 (bias row; wb blob has 0 there so vv is unaffected), k>59 -> 0.
static __device__ __forceinline__ void frags_from_lds(
    const float* __restrict__ xs, int row, int lg, short8* a)
{
    const float* r = xs + row * FF;
    float xv[8];
    #pragma unroll
    for (int j = 0; j < 8; ++j) xv[j] = r[lg * 8 + j];
    #pragma unroll
    for (int j = 0; j < 8; ++j) a[0][j] = (short)f2bf(xv[j]);
    if (lg < 3) {
        #pragma unroll
        for (int j = 0; j < 8; ++j) xv[j] = r[32 + lg * 8 + j];
    } else {
        xv[0] = r[56]; xv[1] = r[57]; xv[2] = r[58]; xv[3] = 1.0f;
        #pragma unroll
        for (int j = 4; j < 8; ++j) xv[j] = 0.0f;
    }
    #pragma unroll
    for (int j = 0; j < 8; ++j) a[1][j] = (short)f2bf(xv[j]);
}

// ---------------------------------------------------------------------------
// Kernel B: build wu blob (blocks 0..15) and wb blob (blocks 16..31).
// frag (s,nt) at ((s*8+nt)*64 + lane)*8 shorts; lane gives d = nt*16+(l&15),
// k0 = s*32+(l>>4)*8 — exactly the MFMA B-fragment each lane needs.
// ---------------------------------------------------------------------------
__global__ __launch_bounds__(64) void ecn_blob(
    const float* __restrict__ w1, const float* __restrict__ b1,
    short* __restrict__ blob)
{
    const int bid = blockIdx.x;
    const int l = threadIdx.x;
    const bool isB = (bid >= 16);
    const int fid = isB ? (bid - 16) : bid;
    const int s = fid >> 3, nt = fid & 7;
    const int lr = l & 15, lg = l >> 4;
    const int d = nt * 16 + lr, k0 = s * 32 + lg * 8;
    short8 pk;
    #pragma unroll
    for (int j = 0; j < 8; ++j) {
        int k = k0 + j;
        float v = 0.0f;
        if (k < FF) {
            float wb_ = w1[(size_t)(FF + k) * D1 + d];
            v = isB ? wb_ : (w1[(size_t)k * D1 + d] - wb_);
        } else if (k == FF && !isB) {
            v = b1[d];                       // bias row only in wu
        }
        pk[j] = (short)f2bf(v);
    }
    *(short8*)&blob[(size_t)(isB ? WS_WB_SHORTS : 0) + ((s * 8 + nt) * 64 + l) * 8] = pk;
}

// ---------------------------------------------------------------------------
// Kernel F: per-graph fused. global_load_lds x-staging + distributed vv +
// per-nt streaming u-GEMM + epilogue + BN1 + head MLP + sigmoid.
// ---------------------------------------------------------------------------
__global__ __launch_bounds__(256, 4) void ecn_fused(
    const float* __restrict__ x, const short* __restrict__ blob,
    const float* __restrict__ g1, const float* __restrict__ be1,
    const float* __restrict__ m1, const float* __restrict__ v1,
    const float* __restrict__ w2, const float* __restrict__ b2,
    const float* __restrict__ g2, const float* __restrict__ be2,
    const float* __restrict__ m2, const float* __restrict__ v2,
    const float* __restrict__ w3, const float* __restrict__ b3,
    const float* __restrict__ g3, const float* __restrict__ be3,
    const float* __restrict__ m3, const float* __restrict__ v3,
    float* __restrict__ out)
{
    // XCD-aware bijective swizzle: 1000 = 8 * 125
    const int bid = blockIdx.x;
    const int g = (bid & 7) * 125 + (bid >> 3);
    const int t = threadIdx.x;

    __shared__ __align__(16) float xs[NPG * FF];   // 30208 B, linear f32 image
    __shared__ float vvsh[4 * D1];   // 2 KB
    __shared__ float Sp[4][D1];      // 2 KB
    __shared__ float x2s[D1];        // 512 B
    __shared__ float rpart[4];
    // total ~35 KB -> 4 blocks/CU

    // ---- stage x: 1888 float4 chunks via global_load_lds (direct-to-LDS) ----
    {
        const float4* xg4 = (const float4*)(x + (size_t)g * NPG * FF);
        float4* xs4 = (float4*)xs;
        #pragma unroll
        for (int k = 0; k < 8; ++k) {
            int e = t + k * 256;
            if (k < 7 || e < 1888)
                __builtin_amdgcn_global_load_lds(&xg4[e], &xs4[e], 16, 0, 0);
        }
    }
    __syncthreads();   // drains vmcnt (incl. global_load_lds) + barrier

    const int wave = t >> 6, l = t & 63;
    const int lr = l & 15, lg = l >> 4;
    const int i0 = wave * 32 + lr;        // mt=0 row
    const int i1 = i0 + 16;               // mt=1 row

    const short8* wu8 = (const short8*)blob;
    const short8* wb8 = (const short8*)(blob + WS_WB_SHORTS);

    // ---- A fragments from LDS: rows i0, i1 (u-GEMM) and row lr (vv tile) ----
    short8 a0[2], a1[2], av[2];
    frags_from_lds(xs, i0, lg, a0);
    frags_from_lds(xs, i1, lg, a1);
    if (wave == 0) { av[0] = a0[0]; av[1] = a0[1]; }   // wave 0: lr == i0
    else           frags_from_lds(xs, lr, lg, av);

    // ---- vv: this wave computes nt-tiles {2*wave, 2*wave+1} of x_{0..15}@w1b ----
    #pragma unroll
    for (int p = 0; p < 2; ++p) {
        const int nt = wave * 2 + p;
        f32x4 cv = (f32x4)0.0f;
        cv = __builtin_amdgcn_mfma_f32_16x16x32_bf16(av[0], wb8[nt * 64 + l],       cv, 0, 0, 0);
        cv = __builtin_amdgcn_mfma_f32_16x16x32_bf16(av[1], wb8[(8 + nt) * 64 + l], cv, 0, 0, 0);
        if (lg == 0) {                    // rows 0..3 = lanes 0..15, q=0..3
            #pragma unroll
            for (int q = 0; q < 4; ++q) vvsh[q * D1 + nt * 16 + lr] = cv[q];
        }
    }
    __syncthreads();                      // vvsh complete

    // ---- per-nt streaming u-GEMM + fused relu-edge aggregation ----
    #pragma unroll
    for (int nt = 0; nt < 8; ++nt) {
        short8 b0 = wu8[nt * 64 + l];
        short8 b1f = wu8[(8 + nt) * 64 + l];
        f32x4 c0 = (f32x4)0.0f, c1 = (f32x4)0.0f;
        c0 = __builtin_amdgcn_mfma_f32_16x16x32_bf16(a0[0], b0,  c0, 0, 0, 0);
        c0 = __builtin_amdgcn_mfma_f32_16x16x32_bf16(a0[1], b1f, c0, 0, 0, 0);
        c1 = __builtin_amdgcn_mfma_f32_16x16x32_bf16(a1[0], b0,  c1, 0, 0, 0);
        c1 = __builtin_amdgcn_mfma_f32_16x16x32_bf16(a1[1], b1f, c1, 0, 0, 0);

        const int d = nt * 16 + lr;
        const float v0 = vvsh[d], v1_ = vvsh[128 + d], v2_ = vvsh[256 + d], v3_ = vvsh[384 + d];
        float s = 0.0f;
        #pragma unroll
        for (int q = 0; q < 4; ++q) {
            float u = c0[q];              // b1 already inside via k=59 row
            s += fmaxf(u + v0, 0.0f) + fmaxf(u + v1_, 0.0f) + fmaxf(u + v2_, 0.0f);
            u = c1[q];
            s += fmaxf(u + v0, 0.0f) + fmaxf(u + v1_, 0.0f) + fmaxf(u + v2_, 0.0f);
        }
        if (wave == 0 && lg == 0) {       // global rows 0,1,2 = c0 q=0..2
            float u0 = c0[0], u1 = c0[1], u2 = c0[2];
            s += fmaxf(u0 + v3_, 0.0f) - fmaxf(u0 + v0,  0.0f);
            s += fmaxf(u1 + v3_, 0.0f) - fmaxf(u1 + v1_, 0.0f);
            s += fmaxf(u2 + v3_, 0.0f) - fmaxf(u2 + v2_, 0.0f);
        }
        s += __shfl_xor(s, 16);
        s += __shfl_xor(s, 32);
        if (lg == 0) Sp[wave][d] = s;
    }
    __syncthreads();

    // ---- BN1 (affine commutes with the means) -> x2 in LDS ----
    if (t < D1) {
        float tot = Sp[0][t] + Sp[1][t] + Sp[2][t] + Sp[3][t];
        float sc = g1[t] * rsqrtf(v1[t] + EPSV);
        x2s[t] = sc * (tot * (1.0f / (3 * NPG))) + (be1[t] - m1[t] * sc);
    }
    __syncthreads();

    // ---- head MLP + sigmoid (4 independent FMA chains for ILP) ----
    {
        float h0 = b2[t], h1 = 0.0f, h2 = 0.0f, h3 = 0.0f;
        #pragma unroll 8
        for (int f = 0; f < D1; f += 4) {
            h0 = fmaf(x2s[f],     w2[(size_t)f * D2 + t],       h0);
            h1 = fmaf(x2s[f + 1], w2[(size_t)(f + 1) * D2 + t], h1);
            h2 = fmaf(x2s[f + 2], w2[(size_t)(f + 2) * D2 + t], h2);
            h3 = fmaf(x2s[f + 3], w2[(size_t)(f + 3) * D2 + t], h3);
        }
        float h = (h0 + h1) + (h2 + h3);
        h = fmaxf(h, 0.0f);
        float sc2 = g2[t] * rsqrtf(v2[t] + EPSV);
        h = sc2 * h + (be2[t] - m2[t] * sc2);
        float r = h * w3[t];
        #pragma unroll
        for (int off = 32; off > 0; off >>= 1) r += __shfl_down(r, off);
        if ((t & 63) == 0) rpart[t >> 6] = r;
    }
    __syncthreads();
    if (t == 0) {
        float s = rpart[0] + rpart[1] + rpart[2] + rpart[3] + b3[0];
        s = fmaxf(s, 0.0f);
        float sc3 = g3[0] * rsqrtf(v3[0] + EPSV);
        s = sc3 * s + (be3[0] - m3[0] * sc3);
        out[g] = 1.0f / (1.0f + expf(-s));
    }
}

extern "C" void kernel_launch(void* const* d_in, const int* in_sizes, int n_in,
                              void* d_out, int out_size, void* d_ws, size_t ws_size,
                              hipStream_t stream) {
    const float* x   = (const float*)d_in[0];
    // d_in[1] = pos — unused: the reference's knn degenerates (see NOTE)
    const float* w1  = (const float*)d_in[2];
    const float* b1  = (const float*)d_in[3];
    const float* g1  = (const float*)d_in[4];
    const float* be1 = (const float*)d_in[5];
    const float* m1  = (const float*)d_in[6];
    const float* v1  = (const float*)d_in[7];
    const float* w2  = (const float*)d_in[8];
    const float* b2  = (const float*)d_in[9];
    const float* g2  = (const float*)d_in[10];
    const float* be2 = (const float*)d_in[11];
    const float* m2  = (const float*)d_in[12];
    const float* v2  = (const float*)d_in[13];
    const float* w3  = (const float*)d_in[14];
    const float* b3  = (const float*)d_in[15];
    const float* g3  = (const float*)d_in[16];
    const float* be3 = (const float*)d_in[17];
    const float* m3  = (const float*)d_in[18];
    const float* v3  = (const float*)d_in[19];
    float* outp = (float*)d_out;

    short* blob = (short*)d_ws;

    ecn_blob<<<32, 64, 0, stream>>>(w1, b1, blob);
    ecn_fused<<<NG, 256, 0, stream>>>(x, blob, g1, be1, m1, v1,
                                      w2, b2, g2, be2, m2, v2,
                                      w3, b3, g3, be3, m3, v3, outp);
}